// Round 1
// baseline (490.905 us; speedup 1.0000x reference)
//
#include <hip/hip_runtime.h>
#include <hip/hip_bf16.h>
#include <math.h>

typedef float v4f __attribute__((ext_vector_type(4)));
typedef short v8s __attribute__((ext_vector_type(8)));

#define T_TOK   2048
#define DDIM    1024
#define NE      16
#define IDIM    512
#define S_ROUTED 8192
#define S_ALL   10240
#define MAXTILE 100

// ---- workspace layout (bytes) ----
#define OFF_COUNTS   0           // 17 ints (zeroed by memset)
#define OFF_FILLS    128         // 17 ints (zeroed by memset)
#define OFF_NTILES   256         // 1 int
#define OFF_SEGOFF   512         // 18 ints
#define OFF_TROW     1024        // MAXTILE ints
#define OFF_TEND     1536        // MAXTILE ints
#define OFF_TEXP     2048        // MAXTILE ints
#define OFF_TOPKI    4096        // 8192 ints
#define OFF_TOPKW    36864       // 8192 floats
#define OFF_SLOTWT   69632       // 10240 floats
#define OFF_SLOTOF   110592      // 8192 ints
#define OFF_XBF      (1u<<20)    // 2048*1024 bf16 = 4 MB
#define OFF_XG       (5u<<20)    // (10240+128)*1024 bf16 ≈ 20.25 MB
#define OFF_H        (27u<<20)   // (10240+128)*512 bf16 ≈ 10.1 MB
#define OFF_YP       (38u<<20)   // 10240*1024 fp32 = 40 MB  (ends ~78 MB)

__device__ __forceinline__ unsigned short f2bf(float f) {
    unsigned int u = __float_as_uint(f);
    unsigned int r = (u + 0x7fffu + ((u >> 16) & 1u)) >> 16;
    return (unsigned short)r;
}

// ---------------- gate: fp32 logits, softmax, group-limited top-4 ----------------
__global__ __launch_bounds__(64) void gate_kernel(
    const float* __restrict__ x, const float* __restrict__ gw,
    int* __restrict__ counts, int* __restrict__ topki, float* __restrict__ topkw,
    unsigned short* __restrict__ xbf)
{
    int t = blockIdx.x;
    int lane = threadIdx.x;
    const float4* xr = (const float4*)(x + (size_t)t * DDIM);
    float4 xv[4];
#pragma unroll
    for (int j = 0; j < 4; j++) xv[j] = xr[lane + 64 * j];

    __shared__ float sc[NE];
#pragma unroll 1
    for (int e = 0; e < NE; e++) {
        const float4* wr = (const float4*)(gw + (size_t)e * DDIM);
        float acc = 0.f;
#pragma unroll
        for (int j = 0; j < 4; j++) {
            float4 w = wr[lane + 64 * j];
            acc += xv[j].x * w.x + xv[j].y * w.y + xv[j].z * w.z + xv[j].w * w.w;
        }
#pragma unroll
        for (int off = 32; off; off >>= 1) acc += __shfl_down(acc, off, 64);
        if (lane == 0) sc[e] = acc;
    }
    // bf16 copy of x row (round-to-nearest-even)
#pragma unroll
    for (int j = 0; j < 4; j++) {
        int base = 4 * (lane + 64 * j);
        uint2 p;
        p.x = (unsigned)f2bf(xv[j].x) | ((unsigned)f2bf(xv[j].y) << 16);
        p.y = (unsigned)f2bf(xv[j].z) | ((unsigned)f2bf(xv[j].w) << 16);
        *(uint2*)(xbf + (size_t)t * DDIM + base) = p;
    }
    __syncthreads();
    if (lane == 0) {
        float mx = sc[0];
#pragma unroll
        for (int e = 1; e < NE; e++) mx = fmaxf(mx, sc[e]);
        float sco[NE]; float sum = 0.f;
#pragma unroll
        for (int e = 0; e < NE; e++) { sco[e] = __expf(sc[e] - mx); sum += sco[e]; }
        float inv = 1.f / sum;
#pragma unroll
        for (int e = 0; e < NE; e++) sco[e] *= inv;
        // group scores (4 groups of 4), top-2 groups, tie -> lower index
        float gs[4];
#pragma unroll
        for (int g = 0; g < 4; g++) {
            float m = sco[4 * g];
            m = fmaxf(m, sco[4 * g + 1]); m = fmaxf(m, sco[4 * g + 2]); m = fmaxf(m, sco[4 * g + 3]);
            gs[g] = m;
        }
        int g0 = 0;
        for (int g = 1; g < 4; g++) if (gs[g] > gs[g0]) g0 = g;
        int g1 = -1;
        for (int g = 0; g < 4; g++) { if (g == g0) continue; if (g1 < 0 || gs[g] > gs[g1]) g1 = g; }
        float ms[NE];
#pragma unroll
        for (int e = 0; e < NE; e++) {
            int g = e >> 2;
            ms[e] = (g == g0 || g == g1) ? sco[e] : 0.0f;
        }
        bool used[NE] = {false};
        for (int k = 0; k < 4; k++) {
            int best = -1;
            for (int e = 0; e < NE; e++) {
                if (used[e]) continue;
                if (best < 0 || ms[e] > ms[best]) best = e;
            }
            used[best] = true;
            topki[t * 4 + k] = best;
            topkw[t * 4 + k] = sco[best];   // weights from ORIGINAL scores, ROUTE_SCALE=1
            atomicAdd(&counts[best], 1);
        }
    }
}

// ---------------- plan: segment offsets + row-tile table ----------------
__global__ void plan_kernel(int* __restrict__ counts, int* __restrict__ segoff,
                            int* __restrict__ trow, int* __restrict__ tend,
                            int* __restrict__ texp, int* __restrict__ ntp)
{
    if (threadIdx.x != 0 || blockIdx.x != 0) return;
    counts[16] = T_TOK;             // shared expert segment
    int off = 0;
    for (int e = 0; e < 17; e++) { segoff[e] = off; off += counts[e]; }
    segoff[17] = off;               // == 10240
    int nt = 0;
    for (int e = 0; e < 17; e++) {
        int n = counts[e];
        for (int m = 0; m < n && nt < MAXTILE; m += 128) {
            trow[nt] = segoff[e] + m;
            tend[nt] = segoff[e] + n;
            texp[nt] = e;
            nt++;
        }
    }
    *ntp = nt;
}

// ---------------- scatter + gather rows into expert-sorted xg ----------------
__global__ __launch_bounds__(128) void scatter_gather(
    const int* __restrict__ topki, const float* __restrict__ topkw,
    int* __restrict__ fills, const int* __restrict__ segoff,
    int* __restrict__ slotof, float* __restrict__ slotwt,
    const unsigned short* __restrict__ xbf, unsigned short* __restrict__ xg)
{
    int id = blockIdx.x;
    int t = id / 5;
    int k = id - t * 5;
    __shared__ int s_s;
    if (threadIdx.x == 0) {
        int s; float w;
        if (k < 4) {
            int e = topki[t * 4 + k];
            w = topkw[t * 4 + k];
            int pos = atomicAdd(&fills[e], 1);
            s = segoff[e] + pos;
            slotof[t * 4 + k] = s;
        } else {
            s = S_ROUTED + t;   // shared expert slot
            w = 1.0f;
        }
        slotwt[s] = w;
        s_s = s;
    }
    __syncthreads();
    int s = s_s;
    const uint4* src = (const uint4*)(xbf + (size_t)t * DDIM);
    uint4* dst = (uint4*)(xg + (size_t)s * DDIM);
    dst[threadIdx.x] = src[threadIdx.x];   // 128 thr * 16B = 2048B = full row
}

// ---------------- gemm1: h = silu(Xg W1^T) * (Xg W3^T) * gate_wt  (bf16 out) ----------------
__global__ __launch_bounds__(256) void gemm1_kernel(
    const float* __restrict__ w1, const float* __restrict__ w3,
    const float* __restrict__ wsh1, const float* __restrict__ wsh3,
    const unsigned short* __restrict__ xg, unsigned short* __restrict__ h,
    const float* __restrict__ slotwt,
    const int* __restrict__ trow, const int* __restrict__ tend,
    const int* __restrict__ texp, const int* __restrict__ ntp)
{
    int bid = blockIdx.x;
    int tile = bid >> 2, ct = bid & 3;
    if (tile >= *ntp) return;
    int row0 = trow[tile], rend = tend[tile], e = texp[tile];
    const float* B1 = (e < 16) ? (w1 + (size_t)e * IDIM * DDIM) : wsh1;
    const float* B3 = (e < 16) ? (w3 + (size_t)e * IDIM * DDIM) : wsh3;
    int n0 = ct * 128;

    __shared__ __align__(16) short As[128 * 72];
    __shared__ __align__(16) short B1s[128 * 72];
    __shared__ __align__(16) short B3s[128 * 72];

    int tid = threadIdx.x;
    int lane = tid & 63, wave = tid >> 6;
    int wm = wave & 1, wn = wave >> 1;
    int mq = lane >> 4, nl = lane & 15;

    v4f acc1[4][4], acc3[4][4];
#pragma unroll
    for (int i = 0; i < 4; i++)
#pragma unroll
        for (int j = 0; j < 4; j++) { acc1[i][j] = (v4f)0.f; acc3[i][j] = (v4f)0.f; }

    for (int kc = 0; kc < DDIM; kc += 64) {
        __syncthreads();
        // A: 128 rows x 64 cols bf16 from xg
#pragma unroll
        for (int i = 0; i < 4; i++) {
            int u = tid + 256 * i;
            int r = u >> 3, c = u & 7;
            uint4 v = *(const uint4*)(xg + (size_t)(row0 + r) * DDIM + kc + c * 8);
            *(uint4*)(As + r * 72 + c * 8) = v;
        }
        // B1/B3: fp32 -> bf16 during staging
#pragma unroll
        for (int i = 0; i < 8; i++) {
            int u = tid + 256 * i;
            int r = u >> 4, c = u & 15;
            float4 v = *(const float4*)(B1 + (size_t)(n0 + r) * DDIM + kc + c * 4);
            uint2 p;
            p.x = (unsigned)f2bf(v.x) | ((unsigned)f2bf(v.y) << 16);
            p.y = (unsigned)f2bf(v.z) | ((unsigned)f2bf(v.w) << 16);
            *(uint2*)(B1s + r * 72 + c * 4) = p;
            float4 v3 = *(const float4*)(B3 + (size_t)(n0 + r) * DDIM + kc + c * 4);
            uint2 q;
            q.x = (unsigned)f2bf(v3.x) | ((unsigned)f2bf(v3.y) << 16);
            q.y = (unsigned)f2bf(v3.z) | ((unsigned)f2bf(v3.w) << 16);
            *(uint2*)(B3s + r * 72 + c * 4) = q;
        }
        __syncthreads();
#pragma unroll
        for (int ks = 0; ks < 2; ks++) {
            int kb = ks * 32 + mq * 8;
            v8s a[4], b1[4], b3[4];
#pragma unroll
            for (int mi = 0; mi < 4; mi++)
                a[mi] = *(const v8s*)(As + (wm * 64 + mi * 16 + nl) * 72 + kb);
#pragma unroll
            for (int ni = 0; ni < 4; ni++) {
                b1[ni] = *(const v8s*)(B1s + (wn * 64 + ni * 16 + nl) * 72 + kb);
                b3[ni] = *(const v8s*)(B3s + (wn * 64 + ni * 16 + nl) * 72 + kb);
            }
#pragma unroll
            for (int mi = 0; mi < 4; mi++)
#pragma unroll
                for (int ni = 0; ni < 4; ni++) {
                    acc1[mi][ni] = __builtin_amdgcn_mfma_f32_16x16x32_bf16(a[mi], b1[ni], acc1[mi][ni], 0, 0, 0);
                    acc3[mi][ni] = __builtin_amdgcn_mfma_f32_16x16x32_bf16(a[mi], b3[ni], acc3[mi][ni], 0, 0, 0);
                }
        }
    }
    // epilogue: h = silu(p1)*p3*g   (C/D: col=lane&15, row=(lane>>4)*4+reg)
#pragma unroll
    for (int mi = 0; mi < 4; mi++) {
#pragma unroll
        for (int r = 0; r < 4; r++) {
            int srow = row0 + wm * 64 + mi * 16 + mq * 4 + r;
            if (srow < rend) {
                float g = slotwt[srow];
#pragma unroll
                for (int ni = 0; ni < 4; ni++) {
                    float p1 = acc1[mi][ni][r], p3 = acc3[mi][ni][r];
                    float sig = 1.f / (1.f + __expf(-p1));
                    float hv = p1 * sig * p3 * g;
                    h[(size_t)srow * IDIM + n0 + wn * 64 + ni * 16 + nl] = f2bf(hv);
                }
            }
        }
    }
}

// ---------------- gemm2: yp = h @ W2^T  (fp32 out) ----------------
__global__ __launch_bounds__(256) void gemm2_kernel(
    const float* __restrict__ w2, const float* __restrict__ wsh2,
    const unsigned short* __restrict__ h, float* __restrict__ yp,
    const int* __restrict__ trow, const int* __restrict__ tend,
    const int* __restrict__ texp, const int* __restrict__ ntp)
{
    int bid = blockIdx.x;
    int tile = bid >> 3, ct = bid & 7;
    if (tile >= *ntp) return;
    int row0 = trow[tile], rend = tend[tile], e = texp[tile];
    const float* B = (e < 16) ? (w2 + (size_t)e * DDIM * IDIM) : wsh2;   // [1024][512]
    int n0 = ct * 128;

    __shared__ __align__(16) short As[128 * 72];
    __shared__ __align__(16) short Bs[128 * 72];

    int tid = threadIdx.x;
    int lane = tid & 63, wave = tid >> 6;
    int wm = wave & 1, wn = wave >> 1;
    int mq = lane >> 4, nl = lane & 15;

    v4f acc[4][4];
#pragma unroll
    for (int i = 0; i < 4; i++)
#pragma unroll
        for (int j = 0; j < 4; j++) acc[i][j] = (v4f)0.f;

    for (int kc = 0; kc < IDIM; kc += 64) {
        __syncthreads();
#pragma unroll
        for (int i = 0; i < 4; i++) {
            int u = tid + 256 * i;
            int r = u >> 3, c = u & 7;
            uint4 v = *(const uint4*)(h + (size_t)(row0 + r) * IDIM + kc + c * 8);
            *(uint4*)(As + r * 72 + c * 8) = v;
        }
#pragma unroll
        for (int i = 0; i < 8; i++) {
            int u = tid + 256 * i;
            int r = u >> 4, c = u & 15;
            float4 v = *(const float4*)(B + (size_t)(n0 + r) * IDIM + kc + c * 4);
            uint2 p;
            p.x = (unsigned)f2bf(v.x) | ((unsigned)f2bf(v.y) << 16);
            p.y = (unsigned)f2bf(v.z) | ((unsigned)f2bf(v.w) << 16);
            *(uint2*)(Bs + r * 72 + c * 4) = p;
        }
        __syncthreads();
#pragma unroll
        for (int ks = 0; ks < 2; ks++) {
            int kb = ks * 32 + mq * 8;
            v8s a[4], b[4];
#pragma unroll
            for (int mi = 0; mi < 4; mi++)
                a[mi] = *(const v8s*)(As + (wm * 64 + mi * 16 + nl) * 72 + kb);
#pragma unroll
            for (int ni = 0; ni < 4; ni++)
                b[ni] = *(const v8s*)(Bs + (wn * 64 + ni * 16 + nl) * 72 + kb);
#pragma unroll
            for (int mi = 0; mi < 4; mi++)
#pragma unroll
                for (int ni = 0; ni < 4; ni++)
                    acc[mi][ni] = __builtin_amdgcn_mfma_f32_16x16x32_bf16(a[mi], b[ni], acc[mi][ni], 0, 0, 0);
        }
    }
#pragma unroll
    for (int mi = 0; mi < 4; mi++) {
#pragma unroll
        for (int r = 0; r < 4; r++) {
            int srow = row0 + wm * 64 + mi * 16 + mq * 4 + r;
            if (srow < rend) {
#pragma unroll
                for (int ni = 0; ni < 4; ni++)
                    yp[(size_t)srow * DDIM + n0 + wn * 64 + ni * 16 + nl] = acc[mi][ni][r];
            }
        }
    }
}

// ---------------- combine: out = shared + sum of 4 routed partials ----------------
__global__ __launch_bounds__(256) void combine_kernel(
    const float* __restrict__ yp, const int* __restrict__ slotof, float* __restrict__ out)
{
    int t = blockIdx.x;
    int s0 = slotof[t * 4 + 0], s1 = slotof[t * 4 + 1];
    int s2 = slotof[t * 4 + 2], s3 = slotof[t * 4 + 3];
    for (int d = threadIdx.x; d < DDIM; d += 256) {
        float v = yp[(size_t)(S_ROUTED + t) * DDIM + d];
        v += yp[(size_t)s0 * DDIM + d];
        v += yp[(size_t)s1 * DDIM + d];
        v += yp[(size_t)s2 * DDIM + d];
        v += yp[(size_t)s3 * DDIM + d];
        out[(size_t)t * DDIM + d] = v;
    }
}

extern "C" void kernel_launch(void* const* d_in, const int* in_sizes, int n_in,
                              void* d_out, int out_size, void* d_ws, size_t ws_size,
                              hipStream_t stream) {
    const float* x    = (const float*)d_in[0];
    const float* gw   = (const float*)d_in[1];
    const float* w1   = (const float*)d_in[2];
    const float* w2   = (const float*)d_in[3];
    const float* w3   = (const float*)d_in[4];
    const float* wsh1 = (const float*)d_in[5];
    const float* wsh2 = (const float*)d_in[6];
    const float* wsh3 = (const float*)d_in[7];
    float* out = (float*)d_out;

    char* ws = (char*)d_ws;
    int*   counts = (int*)(ws + OFF_COUNTS);
    int*   fills  = (int*)(ws + OFF_FILLS);
    int*   ntp    = (int*)(ws + OFF_NTILES);
    int*   segoff = (int*)(ws + OFF_SEGOFF);
    int*   trow   = (int*)(ws + OFF_TROW);
    int*   tend   = (int*)(ws + OFF_TEND);
    int*   texp   = (int*)(ws + OFF_TEXP);
    int*   topki  = (int*)(ws + OFF_TOPKI);
    float* topkw  = (float*)(ws + OFF_TOPKW);
    float* slotwt = (float*)(ws + OFF_SLOTWT);
    int*   slotof = (int*)(ws + OFF_SLOTOF);
    unsigned short* xbf = (unsigned short*)(ws + OFF_XBF);
    unsigned short* xg  = (unsigned short*)(ws + OFF_XG);
    unsigned short* h   = (unsigned short*)(ws + OFF_H);
    float* yp = (float*)(ws + OFF_YP);

    hipMemsetAsync(ws, 0, 512, stream);  // counts + fills + ntiles

    gate_kernel<<<T_TOK, 64, 0, stream>>>(x, gw, counts, topki, topkw, xbf);
    plan_kernel<<<1, 64, 0, stream>>>(counts, segoff, trow, tend, texp, ntp);
    scatter_gather<<<T_TOK * 5, 128, 0, stream>>>(topki, topkw, fills, segoff,
                                                  slotof, slotwt, xbf, xg);
    gemm1_kernel<<<MAXTILE * 4, 256, 0, stream>>>(w1, w3, wsh1, wsh3, xg, h, slotwt,
                                                  trow, tend, texp, ntp);
    gemm2_kernel<<<MAXTILE * 8, 256, 0, stream>>>(w2, wsh2, h, yp, trow, tend, texp, ntp);
    combine_kernel<<<T_TOK, 256, 0, stream>>>(yp, slotof, out);
}

// Round 2
// 463.954 us; speedup vs baseline: 1.0581x; 1.0581x over previous
//
#include <hip/hip_runtime.h>
#include <hip/hip_bf16.h>
#include <math.h>

typedef float v4f __attribute__((ext_vector_type(4)));
typedef short v8s __attribute__((ext_vector_type(8)));

#define T_TOK   2048
#define DDIM    1024
#define NE      16
#define IDIM    512
#define S_ROUTED 8192
#define MAXTILE 100
#define EXP_STRIDE (512u*1024u)    // elements per expert weight matrix

// ---- workspace layout (bytes) ----
#define OFF_COUNTS   0           // 17 ints (zeroed by memset)
#define OFF_FILLS    128         // 17 ints (zeroed by memset)
#define OFF_NTILES   256         // 1 int
#define OFF_SEGOFF   512         // 18 ints
#define OFF_TROW     1024
#define OFF_TEND     1536
#define OFF_TEXP     2048
#define OFF_TOPKI    4096        // 8192 ints
#define OFF_TOPKW    36864       // 8192 floats
#define OFF_SLOTWT   69632       // 8192 floats
#define OFF_S2T      102400      // 8192 ints -> ends 135168
#define OFF_XG       (1u<<20)
#define SZ_XG        (10368u*1024u*2u)       // 21,233,664
#define OFF_H        (OFF_XG + SZ_XG)
#define SZ_H         (10368u*512u*2u)        // 10,616,832
#define OFF_W1B      (OFF_H + SZ_H)
#define SZ_WB        (17u*EXP_STRIDE*2u)     // 17,825,792
#define OFF_W3B      (OFF_W1B + SZ_WB)
#define OFF_W2B      (OFF_W3B + SZ_WB)       // ends ~86.4 MB

__device__ __forceinline__ unsigned short f2bf(float f) {
    unsigned int u = __float_as_uint(f);
    unsigned int r = (u + 0x7fffu + ((u >> 16) & 1u)) >> 16;
    return (unsigned short)r;
}

// async global->LDS, 16B per lane, LDS dest = uniform base + lane*16
#define GLL16(gp, lp) __builtin_amdgcn_global_load_lds( \
    (__attribute__((address_space(1))) void*)(gp), \
    (__attribute__((address_space(3))) void*)(lp), 16, 0, 0)

// ---------------- weight convert: fp32 -> bf16, shared expert appended as e=16 ----------------
__global__ __launch_bounds__(256) void convert_kernel(
    const float* __restrict__ w1, const float* __restrict__ w3, const float* __restrict__ w2,
    const float* __restrict__ s1, const float* __restrict__ s3, const float* __restrict__ s2,
    unsigned short* __restrict__ w1b, unsigned short* __restrict__ w3b,
    unsigned short* __restrict__ w2b)
{
    const unsigned MAIN = 16u * EXP_STRIDE;      // 8,388,608
    int which = blockIdx.y;
    const float* msrc = (which == 0) ? w1 : (which == 1) ? w3 : w2;
    const float* ssrc = (which == 0) ? s1 : (which == 1) ? s3 : s2;
    unsigned short* dst = (which == 0) ? w1b : (which == 1) ? w3b : w2b;
    size_t i4 = ((size_t)blockIdx.x * 256 + threadIdx.x) * 4;
    float4 v = (i4 < MAIN) ? *(const float4*)(msrc + i4)
                           : *(const float4*)(ssrc + (i4 - MAIN));
    uint2 p;
    p.x = (unsigned)f2bf(v.x) | ((unsigned)f2bf(v.y) << 16);
    p.y = (unsigned)f2bf(v.z) | ((unsigned)f2bf(v.w) << 16);
    *(uint2*)(dst + i4) = p;
}

// ---------------- gate: fp32 logits, softmax, group-limited top-4 ----------------
__global__ __launch_bounds__(256) void gate_kernel(
    const float* __restrict__ x, const float* __restrict__ gw,
    int* __restrict__ counts, int* __restrict__ topki, float* __restrict__ topkw,
    unsigned short* __restrict__ xbf)
{
    int t = blockIdx.x;
    int tid = threadIdx.x, lane = tid & 63, wave = tid >> 6;
    const float4* xr = (const float4*)(x + (size_t)t * DDIM);
    float4 xv[4];
#pragma unroll
    for (int j = 0; j < 4; j++) xv[j] = xr[lane + 64 * j];

    __shared__ float sc[NE];
#pragma unroll
    for (int ee = 0; ee < 4; ee++) {
        int e = wave * 4 + ee;
        const float4* wr = (const float4*)(gw + (size_t)e * DDIM);
        float acc = 0.f;
#pragma unroll
        for (int j = 0; j < 4; j++) {
            float4 w = wr[lane + 64 * j];
            acc += xv[j].x * w.x + xv[j].y * w.y + xv[j].z * w.z + xv[j].w * w.w;
        }
#pragma unroll
        for (int off = 32; off; off >>= 1) acc += __shfl_down(acc, off, 64);
        if (lane == 0) sc[e] = acc;
    }
    if (wave == 0) {
#pragma unroll
        for (int j = 0; j < 4; j++) {
            int base = 4 * (lane + 64 * j);
            uint2 p;
            p.x = (unsigned)f2bf(xv[j].x) | ((unsigned)f2bf(xv[j].y) << 16);
            p.y = (unsigned)f2bf(xv[j].z) | ((unsigned)f2bf(xv[j].w) << 16);
            *(uint2*)(xbf + (size_t)t * DDIM + base) = p;
        }
    }
    __syncthreads();
    if (tid == 0) {
        float mx = sc[0];
#pragma unroll
        for (int e = 1; e < NE; e++) mx = fmaxf(mx, sc[e]);
        float sco[NE]; float sum = 0.f;
#pragma unroll
        for (int e = 0; e < NE; e++) { sco[e] = __expf(sc[e] - mx); sum += sco[e]; }
        float inv = 1.f / sum;
#pragma unroll
        for (int e = 0; e < NE; e++) sco[e] *= inv;
        float gs[4];
#pragma unroll
        for (int g = 0; g < 4; g++) {
            float m = sco[4 * g];
            m = fmaxf(m, sco[4 * g + 1]); m = fmaxf(m, sco[4 * g + 2]); m = fmaxf(m, sco[4 * g + 3]);
            gs[g] = m;
        }
        int g0 = 0;
        for (int g = 1; g < 4; g++) if (gs[g] > gs[g0]) g0 = g;
        int g1 = -1;
        for (int g = 0; g < 4; g++) { if (g == g0) continue; if (g1 < 0 || gs[g] > gs[g1]) g1 = g; }
        float ms[NE];
#pragma unroll
        for (int e = 0; e < NE; e++) {
            int g = e >> 2;
            ms[e] = (g == g0 || g == g1) ? sco[e] : 0.0f;
        }
        bool used[NE] = {false};
        for (int k = 0; k < 4; k++) {
            int best = -1;
            for (int e = 0; e < NE; e++) {
                if (used[e]) continue;
                if (best < 0 || ms[e] > ms[best]) best = e;
            }
            used[best] = true;
            topki[t * 4 + k] = best;
            topkw[t * 4 + k] = sco[best];
            atomicAdd(&counts[best], 1);
        }
    }
}

// ---------------- plan: segment offsets + row-tile table ----------------
__global__ void plan_kernel(int* __restrict__ counts, int* __restrict__ segoff,
                            int* __restrict__ trow, int* __restrict__ tend,
                            int* __restrict__ texp, int* __restrict__ ntp)
{
    if (threadIdx.x != 0 || blockIdx.x != 0) return;
    counts[16] = T_TOK;
    int off = 0;
    for (int e = 0; e < 17; e++) { segoff[e] = off; off += counts[e]; }
    segoff[17] = off;
    int nt = 0;
    for (int e = 0; e < 17; e++) {
        int n = counts[e];
        for (int m = 0; m < n && nt < MAXTILE; m += 128) {
            trow[nt] = segoff[e] + m;
            tend[nt] = segoff[e] + n;
            texp[nt] = e;
            nt++;
        }
    }
    *ntp = nt;
}

// ---------------- scatter: slot assign + gather bf16 rows ----------------
__global__ __launch_bounds__(128) void scatter_gather(
    const int* __restrict__ topki, const float* __restrict__ topkw,
    int* __restrict__ fills, const int* __restrict__ segoff,
    float* __restrict__ slotwt, int* __restrict__ s2t,
    unsigned short* __restrict__ xg)
{
    int id = blockIdx.x;
    int t = id >> 2, k = id & 3;
    __shared__ int s_s;
    if (threadIdx.x == 0) {
        int e = topki[t * 4 + k];
        int pos = atomicAdd(&fills[e], 1);
        int s = segoff[e] + pos;
        slotwt[s] = topkw[t * 4 + k];
        s2t[s] = t;
        s_s = s;
    }
    __syncthreads();
    int s = s_s;
    const uint4* src = (const uint4*)(xg + ((size_t)S_ROUTED + t) * DDIM);
    uint4* dst = (uint4*)(xg + (size_t)s * DDIM);
    dst[threadIdx.x] = src[threadIdx.x];
}

// ---------------- gemm1: h = silu(Xg W1^T) * (Xg W3^T) * g ----------------
// 512 thr = 8 waves, block tile 128x128, wave tile 64x32, BK=64.
// LDS: unpadded stride-64, XOR-swizzled col-blocks: (row, cb) holds global block cb^(row&7).
__global__ __launch_bounds__(512, 4) void gemm1_kernel(
    const unsigned short* __restrict__ w1b, const unsigned short* __restrict__ w3b,
    const unsigned short* __restrict__ xg, unsigned short* __restrict__ h,
    const float* __restrict__ slotwt,
    const int* __restrict__ trow, const int* __restrict__ tend,
    const int* __restrict__ texp, const int* __restrict__ ntp)
{
    int bid = blockIdx.x;
    int tile = bid >> 2, ct = bid & 3;
    if (tile >= *ntp) return;
    int row0 = trow[tile], rend = tend[tile], e = texp[tile];
    int n0 = ct * 128;
    const unsigned short* B1 = w1b + ((size_t)e * IDIM + n0) * DDIM;
    const unsigned short* B3 = w3b + ((size_t)e * IDIM + n0) * DDIM;

    __shared__ __align__(16) short As[128 * 64];
    __shared__ __align__(16) short B1s[128 * 64];
    __shared__ __align__(16) short B3s[128 * 64];

    int tid = threadIdx.x;
    int lane = tid & 63, wave = tid >> 6;        // 8 waves
    int wm = wave & 1, wn = wave >> 1;           // wm: 64-row half, wn: 32-col quarter
    int mq = lane >> 4, nl = lane & 15;
    int rr = lane >> 3;                          // staging row within 8-row issue
    int cb = (lane & 7) ^ rr;                    // XOR-swizzled global col-block

    v4f acc1[4][2], acc3[4][2];
#pragma unroll
    for (int i = 0; i < 4; i++)
#pragma unroll
        for (int j = 0; j < 2; j++) { acc1[i][j] = (v4f)0.f; acc3[i][j] = (v4f)0.f; }

    for (int kc = 0; kc < DDIM; kc += 64) {
        __syncthreads();
        {
            const unsigned short* gA = xg + (size_t)(row0 + wave * 16 + rr) * DDIM + kc + cb * 8;
            GLL16(gA, As + wave * 1024);
            GLL16(gA + 8 * DDIM, As + wave * 1024 + 512);
            const unsigned short* g1 = B1 + (size_t)(wave * 16 + rr) * DDIM + kc + cb * 8;
            GLL16(g1, B1s + wave * 1024);
            GLL16(g1 + 8 * DDIM, B1s + wave * 1024 + 512);
            const unsigned short* g3 = B3 + (size_t)(wave * 16 + rr) * DDIM + kc + cb * 8;
            GLL16(g3, B3s + wave * 1024);
            GLL16(g3 + 8 * DDIM, B3s + wave * 1024 + 512);
        }
        __syncthreads();
#pragma unroll
        for (int ks = 0; ks < 2; ks++) {
            int kb = ks * 4 + mq;                // k-block 0..7
            v8s a[4], b1[2], b3[2];
#pragma unroll
            for (int mi = 0; mi < 4; mi++) {
                int R = wm * 64 + mi * 16 + nl;
                a[mi] = *(const v8s*)(As + R * 64 + ((kb ^ (nl & 7)) * 8));
            }
#pragma unroll
            for (int ni = 0; ni < 2; ni++) {
                int S = wn * 32 + ni * 16 + nl;
                int off = S * 64 + ((kb ^ (nl & 7)) * 8);
                b1[ni] = *(const v8s*)(B1s + off);
                b3[ni] = *(const v8s*)(B3s + off);
            }
#pragma unroll
            for (int mi = 0; mi < 4; mi++)
#pragma unroll
                for (int ni = 0; ni < 2; ni++) {
                    acc1[mi][ni] = __builtin_amdgcn_mfma_f32_16x16x32_bf16(a[mi], b1[ni], acc1[mi][ni], 0, 0, 0);
                    acc3[mi][ni] = __builtin_amdgcn_mfma_f32_16x16x32_bf16(a[mi], b3[ni], acc3[mi][ni], 0, 0, 0);
                }
        }
    }
#pragma unroll
    for (int mi = 0; mi < 4; mi++) {
#pragma unroll
        for (int r = 0; r < 4; r++) {
            int srow = row0 + wm * 64 + mi * 16 + mq * 4 + r;
            if (srow < rend) {
                float g = (srow < S_ROUTED) ? slotwt[srow] : 1.0f;
#pragma unroll
                for (int ni = 0; ni < 2; ni++) {
                    float p1 = acc1[mi][ni][r], p3 = acc3[mi][ni][r];
                    float sig = 1.f / (1.f + __expf(-p1));
                    float hv = p1 * sig * p3 * g;
                    h[(size_t)srow * IDIM + n0 + wn * 32 + ni * 16 + nl] = f2bf(hv);
                }
            }
        }
    }
}

// ---------------- gemm2: out[t] += h @ W2^T  (fused combine via atomics) ----------------
// 256 thr = 4 waves, block tile 128x128, wave tile 64x64, BK=64, K=512.
__global__ __launch_bounds__(256, 4) void gemm2_kernel(
    const unsigned short* __restrict__ w2b, const unsigned short* __restrict__ h,
    float* __restrict__ out, const int* __restrict__ s2t,
    const int* __restrict__ trow, const int* __restrict__ tend,
    const int* __restrict__ texp, const int* __restrict__ ntp)
{
    int bid = blockIdx.x;
    int tile = bid >> 3, ct = bid & 7;
    if (tile >= *ntp) return;
    int row0 = trow[tile], rend = tend[tile], e = texp[tile];
    int n0 = ct * 128;
    const unsigned short* B = w2b + ((size_t)e * DDIM + n0) * IDIM;

    __shared__ __align__(16) short As[128 * 64];
    __shared__ __align__(16) short Bs[128 * 64];

    int tid = threadIdx.x;
    int lane = tid & 63, wave = tid >> 6;        // 4 waves
    int wm = wave & 1, wn = wave >> 1;
    int mq = lane >> 4, nl = lane & 15;
    int rr = lane >> 3;
    int cb = (lane & 7) ^ rr;

    v4f acc[4][4];
#pragma unroll
    for (int i = 0; i < 4; i++)
#pragma unroll
        for (int j = 0; j < 4; j++) acc[i][j] = (v4f)0.f;

    for (int kc = 0; kc < IDIM; kc += 64) {
        __syncthreads();
        {
            const unsigned short* gA = h + (size_t)(row0 + wave * 32 + rr) * IDIM + kc + cb * 8;
            const unsigned short* gB = B + (size_t)(wave * 32 + rr) * IDIM + kc + cb * 8;
#pragma unroll
            for (int j = 0; j < 4; j++) {
                GLL16(gA + (size_t)(8 * j) * IDIM, As + wave * 2048 + j * 512);
                GLL16(gB + (size_t)(8 * j) * IDIM, Bs + wave * 2048 + j * 512);
            }
        }
        __syncthreads();
#pragma unroll
        for (int ks = 0; ks < 2; ks++) {
            int kb = ks * 4 + mq;
            v8s a[4], b[4];
#pragma unroll
            for (int mi = 0; mi < 4; mi++) {
                int R = wm * 64 + mi * 16 + nl;
                a[mi] = *(const v8s*)(As + R * 64 + ((kb ^ (nl & 7)) * 8));
            }
#pragma unroll
            for (int ni = 0; ni < 4; ni++) {
                int S = wn * 64 + ni * 16 + nl;
                b[ni] = *(const v8s*)(Bs + S * 64 + ((kb ^ (nl & 7)) * 8));
            }
#pragma unroll
            for (int mi = 0; mi < 4; mi++)
#pragma unroll
                for (int ni = 0; ni < 4; ni++)
                    acc[mi][ni] = __builtin_amdgcn_mfma_f32_16x16x32_bf16(a[mi], b[ni], acc[mi][ni], 0, 0, 0);
        }
    }
#pragma unroll
    for (int mi = 0; mi < 4; mi++) {
#pragma unroll
        for (int r = 0; r < 4; r++) {
            int srow = row0 + wm * 64 + mi * 16 + mq * 4 + r;
            if (srow < rend) {
                int t = (srow < S_ROUTED) ? s2t[srow] : (srow - S_ROUTED);
                float* orow = out + (size_t)t * DDIM + n0 + wn * 64 + nl;
#pragma unroll
                for (int ni = 0; ni < 4; ni++)
                    atomicAdd(orow + ni * 16, acc[mi][ni][r]);
            }
        }
    }
}

extern "C" void kernel_launch(void* const* d_in, const int* in_sizes, int n_in,
                              void* d_out, int out_size, void* d_ws, size_t ws_size,
                              hipStream_t stream) {
    const float* x    = (const float*)d_in[0];
    const float* gw   = (const float*)d_in[1];
    const float* w1   = (const float*)d_in[2];
    const float* w2   = (const float*)d_in[3];
    const float* w3   = (const float*)d_in[4];
    const float* wsh1 = (const float*)d_in[5];
    const float* wsh2 = (const float*)d_in[6];
    const float* wsh3 = (const float*)d_in[7];
    float* out = (float*)d_out;

    char* ws = (char*)d_ws;
    int*   counts = (int*)(ws + OFF_COUNTS);
    int*   fills  = (int*)(ws + OFF_FILLS);
    int*   ntp    = (int*)(ws + OFF_NTILES);
    int*   segoff = (int*)(ws + OFF_SEGOFF);
    int*   trow   = (int*)(ws + OFF_TROW);
    int*   tend   = (int*)(ws + OFF_TEND);
    int*   texp   = (int*)(ws + OFF_TEXP);
    int*   topki  = (int*)(ws + OFF_TOPKI);
    float* topkw  = (float*)(ws + OFF_TOPKW);
    float* slotwt = (float*)(ws + OFF_SLOTWT);
    int*   s2t    = (int*)(ws + OFF_S2T);
    unsigned short* xg  = (unsigned short*)(ws + OFF_XG);
    unsigned short* h   = (unsigned short*)(ws + OFF_H);
    unsigned short* w1b = (unsigned short*)(ws + OFF_W1B);
    unsigned short* w3b = (unsigned short*)(ws + OFF_W3B);
    unsigned short* w2b = (unsigned short*)(ws + OFF_W2B);

    hipMemsetAsync(ws, 0, 512, stream);
    hipMemsetAsync(d_out, 0, (size_t)out_size * sizeof(float), stream);

    convert_kernel<<<dim3(8704, 3), 256, 0, stream>>>(w1, w3, w2, wsh1, wsh3, wsh2,
                                                      w1b, w3b, w2b);
    gate_kernel<<<T_TOK, 256, 0, stream>>>(x, gw, counts, topki, topkw,
                                           xg + (size_t)S_ROUTED * DDIM);
    plan_kernel<<<1, 64, 0, stream>>>(counts, segoff, trow, tend, texp, ntp);
    scatter_gather<<<T_TOK * 4, 128, 0, stream>>>(topki, topkw, fills, segoff,
                                                  slotwt, s2t, xg);
    gemm1_kernel<<<MAXTILE * 4, 512, 0, stream>>>(w1b, w3b, xg, h, slotwt,
                                                  trow, tend, texp, ntp);
    gemm2_kernel<<<MAXTILE * 8, 256, 0, stream>>>(w2b, h, out, s2t,
                                                  trow, tend, texp, ntp);
}

// Round 3
// 302.069 us; speedup vs baseline: 1.6251x; 1.5359x over previous
//
#include <hip/hip_runtime.h>
#include <hip/hip_bf16.h>
#include <math.h>

typedef float v4f __attribute__((ext_vector_type(4)));
typedef short v8s __attribute__((ext_vector_type(8)));

#define T_TOK   2048
#define DDIM    1024
#define NE      16
#define IDIM    512
#define S_ROUTED 8192
#define S_ALL   10240
#define MAXTILE 104

// ---- workspace layout (bytes) ----
#define OFF_SEGOFF   0           // 18 ints
#define OFF_NTILES   128         // 1 int
#define OFF_TROW     512
#define OFF_TEND     1024
#define OFF_TEXP     1536
#define OFF_TOPKI    4096        // 8192 ints
#define OFF_TOPKW    36864       // 8192 floats
#define OFF_SLOTWT   69632       // 8192 floats
#define OFF_S2T      102400      // 10240 ints
#define OFF_XBF      (1u<<20)    // 2048*1024 bf16 = 4 MB
#define OFF_H        (8u<<20)    // 10240*512 bf16 = 10.5 MB
#define OFF_W13      (20u<<20)   // 17*1024*1024 bf16 = 34 MB (W1/W3 interleaved per 64-col block)
#define OFF_W2B      (56u<<20)   // 17*512*1024 bf16 = 17 MB   (ends ~73 MB)

__device__ __forceinline__ unsigned short f2bf(float f) {
    unsigned int u = __float_as_uint(f);
    unsigned int r = (u + 0x7fffu + ((u >> 16) & 1u)) >> 16;
    return (unsigned short)r;
}

// async global->LDS, 16B/lane, LDS dest = uniform base + lane*16
#define GLL16(gp, lp) __builtin_amdgcn_global_load_lds( \
    (__attribute__((address_space(1))) void*)(gp), \
    (__attribute__((address_space(3))) void*)(lp), 16, 0, 0)

// ---------------- convert: fp32 -> bf16; shared expert appended as e=16 ----------------
// y=0: w13b[e][r2][d]: r2=nb*128+half*64+rr -> (half? w3:w1)[e][nb*64+rr][d]
// y=1: w2b straight copy
__global__ __launch_bounds__(256) void convert_kernel(
    const float* __restrict__ w1, const float* __restrict__ w3, const float* __restrict__ w2,
    const float* __restrict__ s1, const float* __restrict__ s3, const float* __restrict__ s2,
    unsigned short* __restrict__ w13b, unsigned short* __restrict__ w2b)
{
    size_t gid = (size_t)blockIdx.x * 256 + threadIdx.x;
    size_t i4 = gid * 4;
    const float* src;
    unsigned short* dst;
    if (blockIdx.y == 0) {
        int e = (int)(i4 >> 20);
        int rem = (int)(i4 & 1048575u);
        int r2 = rem >> 10, d = rem & 1023;
        int half = (r2 >> 6) & 1;
        int rsrc = ((r2 >> 7) << 6) + (r2 & 63);
        if (e < 16) src = (half ? w3 : w1) + ((size_t)e * 512 + rsrc) * 1024 + d;
        else        src = (half ? s3 : s1) + (size_t)rsrc * 1024 + d;
        dst = w13b + i4;
    } else {
        if (i4 >= 17u * 524288u) return;
        int e = (int)(i4 >> 19);
        int rem = (int)(i4 & 524287u);
        src = (e < 16) ? (w2 + (size_t)e * 524288 + rem) : (s2 + rem);
        dst = w2b + i4;
    }
    float4 v = *(const float4*)src;
    uint2 p;
    p.x = (unsigned)f2bf(v.x) | ((unsigned)f2bf(v.y) << 16);
    p.y = (unsigned)f2bf(v.z) | ((unsigned)f2bf(v.w) << 16);
    *(uint2*)dst = p;
}

// ---------------- gate: fp32 logits, softmax, group-limited top-4 (NO atomics) ----------------
__global__ __launch_bounds__(256) void gate_kernel(
    const float* __restrict__ x, const float* __restrict__ gw,
    int* __restrict__ topki, float* __restrict__ topkw,
    unsigned short* __restrict__ xbf)
{
    int t = blockIdx.x;
    int tid = threadIdx.x, lane = tid & 63, wave = tid >> 6;
    const float4* xr = (const float4*)(x + (size_t)t * DDIM);
    float4 xv[4];
#pragma unroll
    for (int j = 0; j < 4; j++) xv[j] = xr[lane + 64 * j];

    __shared__ float sc[NE];
#pragma unroll
    for (int ee = 0; ee < 4; ee++) {
        int e = wave * 4 + ee;
        const float4* wr = (const float4*)(gw + (size_t)e * DDIM);
        float acc = 0.f;
#pragma unroll
        for (int j = 0; j < 4; j++) {
            float4 w = wr[lane + 64 * j];
            acc += xv[j].x * w.x + xv[j].y * w.y + xv[j].z * w.z + xv[j].w * w.w;
        }
#pragma unroll
        for (int off = 32; off; off >>= 1) acc += __shfl_down(acc, off, 64);
        if (lane == 0) sc[e] = acc;
    }
    if (wave == 0) {
#pragma unroll
        for (int j = 0; j < 4; j++) {
            int base = 4 * (lane + 64 * j);
            uint2 p;
            p.x = (unsigned)f2bf(xv[j].x) | ((unsigned)f2bf(xv[j].y) << 16);
            p.y = (unsigned)f2bf(xv[j].z) | ((unsigned)f2bf(xv[j].w) << 16);
            *(uint2*)(xbf + (size_t)t * DDIM + base) = p;
        }
    }
    __syncthreads();
    if (tid == 0) {
        float mx = sc[0];
#pragma unroll
        for (int e = 1; e < NE; e++) mx = fmaxf(mx, sc[e]);
        float sco[NE]; float sum = 0.f;
#pragma unroll
        for (int e = 0; e < NE; e++) { sco[e] = __expf(sc[e] - mx); sum += sco[e]; }
        float inv = 1.f / sum;
#pragma unroll
        for (int e = 0; e < NE; e++) sco[e] *= inv;
        float gs[4];
#pragma unroll
        for (int g = 0; g < 4; g++) {
            float m = sco[4 * g];
            m = fmaxf(m, sco[4 * g + 1]); m = fmaxf(m, sco[4 * g + 2]); m = fmaxf(m, sco[4 * g + 3]);
            gs[g] = m;
        }
        int g0 = 0;
        for (int g = 1; g < 4; g++) if (gs[g] > gs[g0]) g0 = g;
        int g1 = -1;
        for (int g = 0; g < 4; g++) { if (g == g0) continue; if (g1 < 0 || gs[g] > gs[g1]) g1 = g; }
        float ms[NE];
#pragma unroll
        for (int e = 0; e < NE; e++) {
            int g = e >> 2;
            ms[e] = (g == g0 || g == g1) ? sco[e] : 0.0f;
        }
        bool used[NE] = {false};
        for (int k = 0; k < 4; k++) {
            int best = -1;
            for (int e = 0; e < NE; e++) {
                if (used[e]) continue;
                if (best < 0 || ms[e] > ms[best]) best = e;
            }
            used[best] = true;
            topki[t * 4 + k] = best;
            topkw[t * 4 + k] = sco[best];
        }
    }
}

// ---------------- plan: ballot-count histogram + segment offsets + tiles ----------------
__global__ __launch_bounds__(256) void plan_kernel(
    const int* __restrict__ topki, int* __restrict__ segoff,
    int* __restrict__ trow, int* __restrict__ tend,
    int* __restrict__ texp, int* __restrict__ ntp)
{
    __shared__ int cnt[16];
    int tid = threadIdx.x;
    if (tid < 16) cnt[tid] = 0;
    __syncthreads();
    for (int c = 0; c < 8192; c += 256) {
        int me = topki[c + tid];
#pragma unroll
        for (int e = 0; e < 16; e++) {
            unsigned long long mask = __ballot(me == e);
            if ((tid & 63) == 0) atomicAdd(&cnt[e], __popcll(mask));  // LDS atomic, 4/chunk
        }
    }
    __syncthreads();
    if (tid == 0) {
        int so[17]; int off = 0;
        for (int e = 0; e < 16; e++) { so[e] = off; segoff[e] = off; off += cnt[e]; }
        so[16] = off; segoff[16] = off;   // == 8192
        segoff[17] = off + T_TOK;
        int nt = 0;
        for (int e = 0; e < 17; e++) {
            int n = (e < 16) ? cnt[e] : T_TOK;
            for (int m = 0; m < n; m += 128) {
                trow[nt] = so[e] + m; tend[nt] = so[e] + n; texp[nt] = e; nt++;
            }
        }
        *ntp = nt;
    }
}

// ---------------- rank: ballot prefix-scan slot assignment (NO global atomics) ----------------
__global__ __launch_bounds__(256) void rank_kernel(
    const int* __restrict__ topki, const float* __restrict__ topkw,
    const int* __restrict__ segoff, int* __restrict__ s2t, float* __restrict__ slotwt)
{
    int e = blockIdx.x;
    int tid = threadIdx.x;
    if (e == 16) {                       // shared expert: identity slots
        for (int i = tid; i < T_TOK; i += 256) s2t[S_ROUTED + i] = i;
        return;
    }
    int base = segoff[e];
    __shared__ int wsum[4];
    __shared__ int run;
    if (tid == 0) run = 0;
    __syncthreads();
    for (int c = 0; c < 8192; c += 256) {
        int i = c + tid;
        int me = topki[i];
        bool m = (me == e);
        unsigned long long mask = __ballot(m);
        int lane = tid & 63;
        int lrank = __popcll(mask & ((1ull << lane) - 1ull));
        if (lane == 0) wsum[tid >> 6] = __popcll(mask);
        __syncthreads();
        int pre = run;
        for (int w = 0; w < (tid >> 6); w++) pre += wsum[w];
        int total = wsum[0] + wsum[1] + wsum[2] + wsum[3];
        if (m) {
            int slot = base + pre + lrank;
            s2t[slot] = i >> 2;
            slotwt[slot] = topkw[i];
        }
        __syncthreads();
        if (tid == 0) run += total;
    }
}

// ---------------- gemm1: h = silu(X W1^T) * (X W3^T) * g ; indirect A via s2t ----------------
// 256 thr = 4 waves; block tile 128 rows x 64 cols (dual W1/W3 via interleaved B slab of 128 rows).
__global__ __launch_bounds__(256, 4) void gemm1_kernel(
    const unsigned short* __restrict__ w13b, const unsigned short* __restrict__ xbf,
    unsigned short* __restrict__ h, const float* __restrict__ slotwt,
    const int* __restrict__ s2t,
    const int* __restrict__ trow, const int* __restrict__ tend,
    const int* __restrict__ texp, const int* __restrict__ ntp)
{
    int bid = blockIdx.x;
    int tile = bid >> 3, ct = bid & 7;
    if (tile >= *ntp) return;
    int row0 = trow[tile], rend = tend[tile], e = texp[tile];
    int n0 = ct * 64;
    const unsigned short* B = w13b + ((size_t)e << 20) + ((size_t)ct << 17);

    __shared__ __align__(16) short As[128 * 64];
    __shared__ __align__(16) short Bs[128 * 64];

    int tid = threadIdx.x;
    int lane = tid & 63, wave = tid >> 6;
    int wm = wave & 1, wn = wave >> 1;           // 64-row half, 32-col half
    int mq = lane >> 4, nl = lane & 15;
    int rr = lane >> 3, cbl = (lane & 7) ^ rr;   // XOR col-block swizzle

    int tok[4];
#pragma unroll
    for (int j = 0; j < 4; j++)
        tok[j] = s2t[row0 + wave * 32 + j * 8 + rr];

    v4f acc[4][4];
#pragma unroll
    for (int i = 0; i < 4; i++)
#pragma unroll
        for (int j = 0; j < 4; j++) acc[i][j] = (v4f)0.f;

    for (int kc = 0; kc < DDIM; kc += 64) {
        __syncthreads();
#pragma unroll
        for (int j = 0; j < 4; j++) {
            GLL16(xbf + (size_t)tok[j] * DDIM + kc + cbl * 8, As + wave * 2048 + j * 512);
            GLL16(B + (size_t)(wave * 32 + j * 8 + rr) * DDIM + kc + cbl * 8, Bs + wave * 2048 + j * 512);
        }
        __syncthreads();
#pragma unroll
        for (int ks = 0; ks < 2; ks++) {
            int kb = ks * 4 + mq;
            v8s a[4], b[4];
#pragma unroll
            for (int mi = 0; mi < 4; mi++) {
                int R = wm * 64 + mi * 16 + nl;
                a[mi] = *(const v8s*)(As + R * 64 + ((kb ^ (nl & 7)) * 8));
            }
#pragma unroll
            for (int ni = 0; ni < 4; ni++) {
                int S = (ni >> 1) * 64 + wn * 32 + (ni & 1) * 16 + nl;  // 0,1: W1  2,3: W3
                b[ni] = *(const v8s*)(Bs + S * 64 + ((kb ^ (nl & 7)) * 8));
            }
#pragma unroll
            for (int mi = 0; mi < 4; mi++)
#pragma unroll
                for (int ni = 0; ni < 4; ni++)
                    acc[mi][ni] = __builtin_amdgcn_mfma_f32_16x16x32_bf16(a[mi], b[ni], acc[mi][ni], 0, 0, 0);
        }
    }
#pragma unroll
    for (int mi = 0; mi < 4; mi++) {
#pragma unroll
        for (int r = 0; r < 4; r++) {
            int srow = row0 + wm * 64 + mi * 16 + mq * 4 + r;
            if (srow < rend) {
                float g = (srow < S_ROUTED) ? slotwt[srow] : 1.0f;
#pragma unroll
                for (int ni = 0; ni < 2; ni++) {
                    float p1 = acc[mi][ni][r], p3 = acc[mi][ni + 2][r];
                    float sig = 1.f / (1.f + __expf(-p1));
                    h[(size_t)srow * IDIM + n0 + wn * 32 + ni * 16 + nl] = f2bf(p1 * sig * p3 * g);
                }
            }
        }
    }
}

// ---------------- gemm2: out[t] += h @ W2^T (fused combine via atomics) ----------------
// 256 thr = 4 waves; block tile 128 rows x 128 cols; K=512.
__global__ __launch_bounds__(256, 4) void gemm2_kernel(
    const unsigned short* __restrict__ w2b, const unsigned short* __restrict__ h,
    float* __restrict__ out, const int* __restrict__ s2t,
    const int* __restrict__ trow, const int* __restrict__ tend,
    const int* __restrict__ texp, const int* __restrict__ ntp)
{
    int bid = blockIdx.x;
    int tile = bid >> 3, ct = bid & 7;
    if (tile >= *ntp) return;
    int row0 = trow[tile], rend = tend[tile], e = texp[tile];
    int n0 = ct * 128;
    const unsigned short* B = w2b + ((size_t)e * DDIM + n0) * IDIM;

    __shared__ __align__(16) short As[128 * 64];
    __shared__ __align__(16) short Bs[128 * 64];

    int tid = threadIdx.x;
    int lane = tid & 63, wave = tid >> 6;
    int wm = wave & 1, wn = wave >> 1;
    int mq = lane >> 4, nl = lane & 15;
    int rr = lane >> 3, cbl = (lane & 7) ^ rr;

    v4f acc[4][4];
#pragma unroll
    for (int i = 0; i < 4; i++)
#pragma unroll
        for (int j = 0; j < 4; j++) acc[i][j] = (v4f)0.f;

    for (int kc = 0; kc < IDIM; kc += 64) {
        __syncthreads();
#pragma unroll
        for (int j = 0; j < 4; j++) {
            GLL16(h + (size_t)(row0 + wave * 32 + j * 8 + rr) * IDIM + kc + cbl * 8,
                  As + wave * 2048 + j * 512);
            GLL16(B + (size_t)(wave * 32 + j * 8 + rr) * IDIM + kc + cbl * 8,
                  Bs + wave * 2048 + j * 512);
        }
        __syncthreads();
#pragma unroll
        for (int ks = 0; ks < 2; ks++) {
            int kb = ks * 4 + mq;
            v8s a[4], b[4];
#pragma unroll
            for (int mi = 0; mi < 4; mi++) {
                int R = wm * 64 + mi * 16 + nl;
                a[mi] = *(const v8s*)(As + R * 64 + ((kb ^ (nl & 7)) * 8));
            }
#pragma unroll
            for (int ni = 0; ni < 4; ni++) {
                int S = wn * 64 + ni * 16 + nl;
                b[ni] = *(const v8s*)(Bs + S * 64 + ((kb ^ (nl & 7)) * 8));
            }
#pragma unroll
            for (int mi = 0; mi < 4; mi++)
#pragma unroll
                for (int ni = 0; ni < 4; ni++)
                    acc[mi][ni] = __builtin_amdgcn_mfma_f32_16x16x32_bf16(a[mi], b[ni], acc[mi][ni], 0, 0, 0);
        }
    }
#pragma unroll
    for (int mi = 0; mi < 4; mi++) {
#pragma unroll
        for (int r = 0; r < 4; r++) {
            int srow = row0 + wm * 64 + mi * 16 + mq * 4 + r;
            if (srow < rend) {
                int t = s2t[srow];
                float* orow = out + (size_t)t * DDIM + n0 + wn * 64 + nl;
#pragma unroll
                for (int ni = 0; ni < 4; ni++)
                    atomicAdd(orow + ni * 16, acc[mi][ni][r]);
            }
        }
    }
}

extern "C" void kernel_launch(void* const* d_in, const int* in_sizes, int n_in,
                              void* d_out, int out_size, void* d_ws, size_t ws_size,
                              hipStream_t stream) {
    const float* x    = (const float*)d_in[0];
    const float* gw   = (const float*)d_in[1];
    const float* w1   = (const float*)d_in[2];
    const float* w2   = (const float*)d_in[3];
    const float* w3   = (const float*)d_in[4];
    const float* wsh1 = (const float*)d_in[5];
    const float* wsh2 = (const float*)d_in[6];
    const float* wsh3 = (const float*)d_in[7];
    float* out = (float*)d_out;

    char* ws = (char*)d_ws;
    int*   segoff = (int*)(ws + OFF_SEGOFF);
    int*   ntp    = (int*)(ws + OFF_NTILES);
    int*   trow   = (int*)(ws + OFF_TROW);
    int*   tend   = (int*)(ws + OFF_TEND);
    int*   texp   = (int*)(ws + OFF_TEXP);
    int*   topki  = (int*)(ws + OFF_TOPKI);
    float* topkw  = (float*)(ws + OFF_TOPKW);
    float* slotwt = (float*)(ws + OFF_SLOTWT);
    int*   s2t    = (int*)(ws + OFF_S2T);
    unsigned short* xbf  = (unsigned short*)(ws + OFF_XBF);
    unsigned short* h    = (unsigned short*)(ws + OFF_H);
    unsigned short* w13b = (unsigned short*)(ws + OFF_W13);
    unsigned short* w2b  = (unsigned short*)(ws + OFF_W2B);

    hipMemsetAsync(d_out, 0, (size_t)out_size * sizeof(float), stream);

    convert_kernel<<<dim3(17408, 2), 256, 0, stream>>>(w1, w3, w2, wsh1, wsh3, wsh2,
                                                       w13b, w2b);
    gate_kernel<<<T_TOK, 256, 0, stream>>>(x, gw, topki, topkw, xbf);
    plan_kernel<<<1, 256, 0, stream>>>(topki, segoff, trow, tend, texp, ntp);
    rank_kernel<<<17, 256, 0, stream>>>(topki, topkw, segoff, s2t, slotwt);
    gemm1_kernel<<<MAXTILE * 8, 256, 0, stream>>>(w13b, xbf, h, slotwt, s2t,
                                                  trow, tend, texp, ntp);
    gemm2_kernel<<<MAXTILE * 8, 256, 0, stream>>>(w2b, h, out, s2t,
                                                  trow, tend, texp, ntp);
}

// Round 4
// 232.915 us; speedup vs baseline: 2.1077x; 1.2969x over previous
//
#include <hip/hip_runtime.h>
#include <hip/hip_bf16.h>
#include <math.h>

typedef float v4f __attribute__((ext_vector_type(4)));
typedef short v8s __attribute__((ext_vector_type(8)));

#define T_TOK   2048
#define DDIM    1024
#define NE      16
#define IDIM    512
#define S_ROUTED 8192
#define S_ALL   10240
#define MAXTILE 104

// ---- workspace layout (bytes) ----
#define OFF_TOPKI    0u          // 8192 ints
#define OFF_TOPKW    32768u      // 8192 floats
#define OFF_PART     65536u      // 32*16 ints
#define OFF_CBASE    69632u      // 32*16 ints
#define OFF_SEGOFF   73728u      // 18 ints
#define OFF_NTILES   74240u
#define OFF_TROW     74752u      // MAXTILE ints
#define OFF_TEND     75776u
#define OFF_TEXP     76800u
#define OFF_SLOTWT   81920u      // 8192 floats
#define OFF_S2T      114688u     // 10240 ints
#define OFF_SLOTOF   155648u     // 8192 ints -> ends ~188 KB
#define OFF_W13      (1u<<20)                    // 17*1024*1024 bf16 = 34 MB
#define SZ_W13       35651584u
#define OFF_XBF      (OFF_W13 + SZ_W13)          // 2048*1024 bf16 = 4 MB
#define OFF_YP       (1u<<20)                    // ALIAS over W13+XBF: 10240*1024 f32 = 40 MB
#define OFF_H        (43u<<20)                   // 10240*512 bf16 = 10 MB
#define OFF_W2B      (56u<<20)                   // 17*512*1024 bf16 = 17 MB, ends ~73 MB

__device__ __forceinline__ unsigned short f2bf(float f) {
    unsigned int u = __float_as_uint(f);
    unsigned int r = (u + 0x7fffu + ((u >> 16) & 1u)) >> 16;
    return (unsigned short)r;
}

// async global->LDS, 16B/lane, LDS dest = uniform base + lane*16
#define GLL16(gp, lp) __builtin_amdgcn_global_load_lds( \
    (__attribute__((address_space(1))) void*)(gp), \
    (__attribute__((address_space(3))) void*)(lp), 16, 0, 0)

// ---------------- convert: fp32 -> bf16; shared expert appended as e=16 ----------------
__global__ __launch_bounds__(256) void convert_kernel(
    const float* __restrict__ w1, const float* __restrict__ w3, const float* __restrict__ w2,
    const float* __restrict__ s1, const float* __restrict__ s3, const float* __restrict__ s2,
    unsigned short* __restrict__ w13b, unsigned short* __restrict__ w2b)
{
    size_t gid = (size_t)blockIdx.x * 256 + threadIdx.x;
    size_t i4 = gid * 4;
    const float* src;
    unsigned short* dst;
    if (blockIdx.y == 0) {
        int e = (int)(i4 >> 20);
        int rem = (int)(i4 & 1048575u);
        int r2 = rem >> 10, d = rem & 1023;
        int half = (r2 >> 6) & 1;
        int rsrc = ((r2 >> 7) << 6) + (r2 & 63);
        if (e < 16) src = (half ? w3 : w1) + ((size_t)e * 512 + rsrc) * 1024 + d;
        else        src = (half ? s3 : s1) + (size_t)rsrc * 1024 + d;
        dst = w13b + i4;
    } else {
        if (i4 >= 17u * 524288u) return;
        int e = (int)(i4 >> 19);
        int rem = (int)(i4 & 524287u);
        src = (e < 16) ? (w2 + (size_t)e * 524288 + rem) : (s2 + rem);
        dst = w2b + i4;
    }
    float4 v = *(const float4*)src;
    uint2 p;
    p.x = (unsigned)f2bf(v.x) | ((unsigned)f2bf(v.y) << 16);
    p.y = (unsigned)f2bf(v.z) | ((unsigned)f2bf(v.w) << 16);
    *(uint2*)dst = p;
}

// ---------------- gate: fp32 logits, softmax, group-limited top-4 ----------------
__global__ __launch_bounds__(256) void gate_kernel(
    const float* __restrict__ x, const float* __restrict__ gw,
    int* __restrict__ topki, float* __restrict__ topkw,
    unsigned short* __restrict__ xbf)
{
    int t = blockIdx.x;
    int tid = threadIdx.x, lane = tid & 63, wave = tid >> 6;
    const float4* xr = (const float4*)(x + (size_t)t * DDIM);
    float4 xv[4];
#pragma unroll
    for (int j = 0; j < 4; j++) xv[j] = xr[lane + 64 * j];

    __shared__ float sc[NE];
#pragma unroll
    for (int ee = 0; ee < 4; ee++) {
        int e = wave * 4 + ee;
        const float4* wr = (const float4*)(gw + (size_t)e * DDIM);
        float acc = 0.f;
#pragma unroll
        for (int j = 0; j < 4; j++) {
            float4 w = wr[lane + 64 * j];
            acc += xv[j].x * w.x + xv[j].y * w.y + xv[j].z * w.z + xv[j].w * w.w;
        }
#pragma unroll
        for (int off = 32; off; off >>= 1) acc += __shfl_down(acc, off, 64);
        if (lane == 0) sc[e] = acc;
    }
    if (wave == 0) {
#pragma unroll
        for (int j = 0; j < 4; j++) {
            int base = 4 * (lane + 64 * j);
            uint2 p;
            p.x = (unsigned)f2bf(xv[j].x) | ((unsigned)f2bf(xv[j].y) << 16);
            p.y = (unsigned)f2bf(xv[j].z) | ((unsigned)f2bf(xv[j].w) << 16);
            *(uint2*)(xbf + (size_t)t * DDIM + base) = p;
        }
    }
    __syncthreads();
    if (tid == 0) {
        float mx = sc[0];
#pragma unroll
        for (int e = 1; e < NE; e++) mx = fmaxf(mx, sc[e]);
        float sco[NE]; float sum = 0.f;
#pragma unroll
        for (int e = 0; e < NE; e++) { sco[e] = __expf(sc[e] - mx); sum += sco[e]; }
        float inv = 1.f / sum;
#pragma unroll
        for (int e = 0; e < NE; e++) sco[e] *= inv;
        float gs[4];
#pragma unroll
        for (int g = 0; g < 4; g++) {
            float m = sco[4 * g];
            m = fmaxf(m, sco[4 * g + 1]); m = fmaxf(m, sco[4 * g + 2]); m = fmaxf(m, sco[4 * g + 3]);
            gs[g] = m;
        }
        int g0 = 0;
        for (int g = 1; g < 4; g++) if (gs[g] > gs[g0]) g0 = g;
        int g1 = -1;
        for (int g = 0; g < 4; g++) { if (g == g0) continue; if (g1 < 0 || gs[g] > gs[g1]) g1 = g; }
        float ms[NE];
#pragma unroll
        for (int e = 0; e < NE; e++) {
            int g = e >> 2;
            ms[e] = (g == g0 || g == g1) ? sco[e] : 0.0f;
        }
        bool used[NE] = {false};
        for (int k = 0; k < 4; k++) {
            int best = -1;
            for (int e = 0; e < NE; e++) {
                if (used[e]) continue;
                if (best < 0 || ms[e] > ms[best]) best = e;
            }
            used[best] = true;
            topki[t * 4 + k] = best;
            topkw[t * 4 + k] = sco[best];
        }
    }
}

// ---------------- hist: per-chunk expert histogram (32 blocks x 256 entries) ----------------
__global__ __launch_bounds__(256) void hist_kernel(
    const int* __restrict__ topki, int* __restrict__ part)
{
    __shared__ int cnt[16];
    int tid = threadIdx.x, b = blockIdx.x;
    if (tid < 16) cnt[tid] = 0;
    __syncthreads();
    int e = topki[b * 256 + tid];
    int lane = tid & 63;
#pragma unroll
    for (int e0 = 0; e0 < 16; e0++) {
        unsigned long long mask = __ballot(e == e0);
        if (lane == 0) atomicAdd(&cnt[e0], __popcll(mask));
    }
    __syncthreads();
    if (tid < 16) part[b * 16 + tid] = cnt[tid];
}

// ---------------- scan: totals -> segoff, chunk bases, tile table (1 block) ----------------
__global__ __launch_bounds__(256) void scan_kernel(
    const int* __restrict__ part, int* __restrict__ cbase, int* __restrict__ segoff,
    int* __restrict__ trow, int* __restrict__ tend, int* __restrict__ texp,
    int* __restrict__ ntp)
{
    int tid = threadIdx.x;
    __shared__ int tot[16];
    __shared__ int so[17];
    if (tid < 16) {
        int s = 0;
        for (int b = 0; b < 32; b++) s += part[b * 16 + tid];
        tot[tid] = s;
    }
    __syncthreads();
    if (tid == 0) {
        int off = 0;
        for (int e = 0; e < 16; e++) { so[e] = off; segoff[e] = off; off += tot[e]; }
        so[16] = off; segoff[16] = off; segoff[17] = off + T_TOK;
        int nt = 0;
        for (int e = 0; e < 17; e++) {
            int n = (e < 16) ? tot[e] : T_TOK;
            int base = (e < 16) ? so[e] : S_ROUTED;
            for (int m = 0; m < n; m += 128) {
                trow[nt] = base + m; tend[nt] = base + n; texp[nt] = e; nt++;
            }
        }
        *ntp = nt;
    }
    __syncthreads();
    if (tid < 16) {
        int run = so[tid];
        for (int b = 0; b < 32; b++) { cbase[b * 16 + tid] = run; run += part[b * 16 + tid]; }
    }
}

// ---------------- assign: block-local ballot rank + chunk base (32 blocks) ----------------
__global__ __launch_bounds__(256) void assign_kernel(
    const int* __restrict__ topki, const float* __restrict__ topkw,
    const int* __restrict__ cbase, int* __restrict__ s2t,
    float* __restrict__ slotwt, int* __restrict__ slotof)
{
    int b = blockIdx.x, tid = threadIdx.x;
    int i = b * 256 + tid;
    int e = topki[i];
    int lane = tid & 63, wave = tid >> 6;
    __shared__ int wcnt[4][16];
    int lrank = 0;
#pragma unroll
    for (int e0 = 0; e0 < 16; e0++) {
        unsigned long long mask = __ballot(e == e0);
        if (e == e0) lrank = __popcll(mask & ((1ull << lane) - 1ull));
        if (lane == 0) wcnt[wave][e0] = __popcll(mask);
    }
    __syncthreads();
    int pre = 0;
    for (int w = 0; w < wave; w++) pre += wcnt[w][e];
    int slot = cbase[b * 16 + e] + pre + lrank;
    int t = i >> 2;
    s2t[slot] = t;
    slotwt[slot] = topkw[i];
    slotof[i] = slot;
    if ((i & 3) == 0) s2t[S_ROUTED + t] = t;   // shared expert identity slots
}

// ---------------- gemm1: h = silu(X W1^T) * (X W3^T) * g ; indirect A via s2t ----------------
__global__ __launch_bounds__(256, 4) void gemm1_kernel(
    const unsigned short* __restrict__ w13b, const unsigned short* __restrict__ xbf,
    unsigned short* __restrict__ h, const float* __restrict__ slotwt,
    const int* __restrict__ s2t,
    const int* __restrict__ trow, const int* __restrict__ tend,
    const int* __restrict__ texp, const int* __restrict__ ntp)
{
    int bid = blockIdx.x;
    int tile = bid >> 3, ct = bid & 7;
    if (tile >= *ntp) return;
    int row0 = trow[tile], rend = tend[tile], e = texp[tile];
    int n0 = ct * 64;
    const unsigned short* B = w13b + ((size_t)e << 20) + ((size_t)ct << 17);

    __shared__ __align__(16) short As[128 * 64];
    __shared__ __align__(16) short Bs[128 * 64];

    int tid = threadIdx.x;
    int lane = tid & 63, wave = tid >> 6;
    int wm = wave & 1, wn = wave >> 1;
    int mq = lane >> 4, nl = lane & 15;
    int rr = lane >> 3, cbl = (lane & 7) ^ rr;

    int tok[4];
#pragma unroll
    for (int j = 0; j < 4; j++)
        tok[j] = s2t[row0 + wave * 32 + j * 8 + rr];

    v4f acc[4][4];
#pragma unroll
    for (int i = 0; i < 4; i++)
#pragma unroll
        for (int j = 0; j < 4; j++) acc[i][j] = (v4f)0.f;

    for (int kc = 0; kc < DDIM; kc += 64) {
        __syncthreads();
#pragma unroll
        for (int j = 0; j < 4; j++) {
            GLL16(xbf + (size_t)tok[j] * DDIM + kc + cbl * 8, As + wave * 2048 + j * 512);
            GLL16(B + (size_t)(wave * 32 + j * 8 + rr) * DDIM + kc + cbl * 8, Bs + wave * 2048 + j * 512);
        }
        __syncthreads();
#pragma unroll
        for (int ks = 0; ks < 2; ks++) {
            int kb = ks * 4 + mq;
            v8s a[4], b[4];
#pragma unroll
            for (int mi = 0; mi < 4; mi++) {
                int R = wm * 64 + mi * 16 + nl;
                a[mi] = *(const v8s*)(As + R * 64 + ((kb ^ (nl & 7)) * 8));
            }
#pragma unroll
            for (int ni = 0; ni < 4; ni++) {
                int S = (ni >> 1) * 64 + wn * 32 + (ni & 1) * 16 + nl;  // 0,1: W1  2,3: W3
                b[ni] = *(const v8s*)(Bs + S * 64 + ((kb ^ (nl & 7)) * 8));
            }
#pragma unroll
            for (int mi = 0; mi < 4; mi++)
#pragma unroll
                for (int ni = 0; ni < 4; ni++)
                    acc[mi][ni] = __builtin_amdgcn_mfma_f32_16x16x32_bf16(a[mi], b[ni], acc[mi][ni], 0, 0, 0);
        }
    }
#pragma unroll
    for (int mi = 0; mi < 4; mi++) {
#pragma unroll
        for (int r = 0; r < 4; r++) {
            int srow = row0 + wm * 64 + mi * 16 + mq * 4 + r;
            if (srow < rend) {
                float g = (srow < S_ROUTED) ? slotwt[srow] : 1.0f;
#pragma unroll
                for (int ni = 0; ni < 2; ni++) {
                    float p1 = acc[mi][ni][r], p3 = acc[mi][ni + 2][r];
                    float sig = 1.f / (1.f + __expf(-p1));
                    h[(size_t)srow * IDIM + n0 + wn * 32 + ni * 16 + nl] = f2bf(p1 * sig * p3 * g);
                }
            }
        }
    }
}

// ---------------- gemm2: yp = h @ W2^T (plain stores, no atomics) ----------------
__global__ __launch_bounds__(256, 4) void gemm2_kernel(
    const unsigned short* __restrict__ w2b, const unsigned short* __restrict__ h,
    float* __restrict__ yp,
    const int* __restrict__ trow, const int* __restrict__ tend,
    const int* __restrict__ texp, const int* __restrict__ ntp)
{
    int bid = blockIdx.x;
    int tile = bid >> 3, ct = bid & 7;
    if (tile >= *ntp) return;
    int row0 = trow[tile], rend = tend[tile], e = texp[tile];
    int n0 = ct * 128;
    const unsigned short* B = w2b + ((size_t)e * DDIM + n0) * IDIM;

    __shared__ __align__(16) short As[128 * 64];
    __shared__ __align__(16) short Bs[128 * 64];

    int tid = threadIdx.x;
    int lane = tid & 63, wave = tid >> 6;
    int wm = wave & 1, wn = wave >> 1;
    int mq = lane >> 4, nl = lane & 15;
    int rr = lane >> 3, cbl = (lane & 7) ^ rr;

    v4f acc[4][4];
#pragma unroll
    for (int i = 0; i < 4; i++)
#pragma unroll
        for (int j = 0; j < 4; j++) acc[i][j] = (v4f)0.f;

    for (int kc = 0; kc < IDIM; kc += 64) {
        __syncthreads();
#pragma unroll
        for (int j = 0; j < 4; j++) {
            GLL16(h + (size_t)(row0 + wave * 32 + j * 8 + rr) * IDIM + kc + cbl * 8,
                  As + wave * 2048 + j * 512);
            GLL16(B + (size_t)(wave * 32 + j * 8 + rr) * IDIM + kc + cbl * 8,
                  Bs + wave * 2048 + j * 512);
        }
        __syncthreads();
#pragma unroll
        for (int ks = 0; ks < 2; ks++) {
            int kb = ks * 4 + mq;
            v8s a[4], b[4];
#pragma unroll
            for (int mi = 0; mi < 4; mi++) {
                int R = wm * 64 + mi * 16 + nl;
                a[mi] = *(const v8s*)(As + R * 64 + ((kb ^ (nl & 7)) * 8));
            }
#pragma unroll
            for (int ni = 0; ni < 4; ni++) {
                int S = wn * 64 + ni * 16 + nl;
                b[ni] = *(const v8s*)(Bs + S * 64 + ((kb ^ (nl & 7)) * 8));
            }
#pragma unroll
            for (int mi = 0; mi < 4; mi++)
#pragma unroll
                for (int ni = 0; ni < 4; ni++)
                    acc[mi][ni] = __builtin_amdgcn_mfma_f32_16x16x32_bf16(a[mi], b[ni], acc[mi][ni], 0, 0, 0);
        }
    }
#pragma unroll
    for (int mi = 0; mi < 4; mi++) {
#pragma unroll
        for (int r = 0; r < 4; r++) {
            int srow = row0 + wm * 64 + mi * 16 + mq * 4 + r;
            if (srow < rend) {
                float* yrow = yp + ((size_t)srow << 10) + n0 + wn * 64 + nl;
#pragma unroll
                for (int ni = 0; ni < 4; ni++)
                    yrow[ni * 16] = acc[mi][ni][r];
            }
        }
    }
}

// ---------------- combine: out[t] = yp[shared_t] + sum of 4 routed yp rows ----------------
__global__ __launch_bounds__(256) void combine_kernel(
    const float* __restrict__ yp, const int* __restrict__ slotof,
    float* __restrict__ out)
{
    int t = blockIdx.x;
    int c = threadIdx.x * 4;
    int s0 = slotof[t * 4 + 0], s1 = slotof[t * 4 + 1];
    int s2 = slotof[t * 4 + 2], s3 = slotof[t * 4 + 3];
    float4 v  = *(const float4*)(yp + (((size_t)(S_ROUTED + t)) << 10) + c);
    float4 a0 = *(const float4*)(yp + (((size_t)s0) << 10) + c);
    float4 a1 = *(const float4*)(yp + (((size_t)s1) << 10) + c);
    float4 a2 = *(const float4*)(yp + (((size_t)s2) << 10) + c);
    float4 a3 = *(const float4*)(yp + (((size_t)s3) << 10) + c);
    v.x += a0.x + a1.x + a2.x + a3.x;
    v.y += a0.y + a1.y + a2.y + a3.y;
    v.z += a0.z + a1.z + a2.z + a3.z;
    v.w += a0.w + a1.w + a2.w + a3.w;
    *(float4*)(out + (((size_t)t) << 10) + c) = v;
}

extern "C" void kernel_launch(void* const* d_in, const int* in_sizes, int n_in,
                              void* d_out, int out_size, void* d_ws, size_t ws_size,
                              hipStream_t stream) {
    const float* x    = (const float*)d_in[0];
    const float* gw   = (const float*)d_in[1];
    const float* w1   = (const float*)d_in[2];
    const float* w2   = (const float*)d_in[3];
    const float* w3   = (const float*)d_in[4];
    const float* wsh1 = (const float*)d_in[5];
    const float* wsh2 = (const float*)d_in[6];
    const float* wsh3 = (const float*)d_in[7];
    float* out = (float*)d_out;

    char* ws = (char*)d_ws;
    int*   topki  = (int*)(ws + OFF_TOPKI);
    float* topkw  = (float*)(ws + OFF_TOPKW);
    int*   part   = (int*)(ws + OFF_PART);
    int*   cbase  = (int*)(ws + OFF_CBASE);
    int*   segoff = (int*)(ws + OFF_SEGOFF);
    int*   ntp    = (int*)(ws + OFF_NTILES);
    int*   trow   = (int*)(ws + OFF_TROW);
    int*   tend   = (int*)(ws + OFF_TEND);
    int*   texp   = (int*)(ws + OFF_TEXP);
    float* slotwt = (float*)(ws + OFF_SLOTWT);
    int*   s2t    = (int*)(ws + OFF_S2T);
    int*   slotof = (int*)(ws + OFF_SLOTOF);
    unsigned short* w13b = (unsigned short*)(ws + OFF_W13);
    unsigned short* xbf  = (unsigned short*)(ws + OFF_XBF);
    float*          yp   = (float*)(ws + OFF_YP);      // aliases w13b+xbf (safe: used after)
    unsigned short* h    = (unsigned short*)(ws + OFF_H);
    unsigned short* w2b  = (unsigned short*)(ws + OFF_W2B);

    convert_kernel<<<dim3(17408, 2), 256, 0, stream>>>(w1, w3, w2, wsh1, wsh3, wsh2,
                                                       w13b, w2b);
    gate_kernel<<<T_TOK, 256, 0, stream>>>(x, gw, topki, topkw, xbf);
    hist_kernel<<<32, 256, 0, stream>>>(topki, part);
    scan_kernel<<<1, 256, 0, stream>>>(part, cbase, segoff, trow, tend, texp, ntp);
    assign_kernel<<<32, 256, 0, stream>>>(topki, topkw, cbase, s2t, slotwt, slotof);
    gemm1_kernel<<<MAXTILE * 8, 256, 0, stream>>>(w13b, xbf, h, slotwt, s2t,
                                                  trow, tend, texp, ntp);
    gemm2_kernel<<<MAXTILE * 8, 256, 0, stream>>>(w2b, h, yp, trow, tend, texp, ntp);
    combine_kernel<<<T_TOK, 256, 0, stream>>>(yp, slotof, out);
}